// Round 9
// baseline (197.355 us; speedup 1.0000x reference)
//
#include <hip/hip_runtime.h>

// PINN fused: u, du/dx0, d2u/dx0^2 of tanh-MLP (2->256->256->256->1), fp32 in/out.
// Round 15: cut the MFMA floor itself (R8/R12/R13 proved overlap levers null;
// closed model: MFMA 47.7 + LDS ~40 + VALU ~20 + barriers ~= 120us measured).
// Swap 16x16x32 -> 32x32x16 f16: 16K FLOP per 8.07cyc vs per 4.85cyc (m119:
// 2495 vs 2075 TF) = 17% fewer matrix-pipe cycles, with IDENTICAL per-wave
// LDS b128 counts (48 B-frags + 32 W-frags per layer), identical A-tile
// layout/swizzle/L1 phase, same 96-VGPR acc (3 streams x 2 strips x 16).
//   - wave owns 2 strips of 32 units; 16 kc-steps of K=16.
//   - C/D map (m74/m101-verified): col=lane&31, row=(reg&3)+8*(reg>>2)+4*(lane>>5)
//     -> E2 still writes half4 at 4 consecutive units; E3 needs only one
//     shfl_xor(32).
//   - prep_w: strips of 32 (frag = W[kc*16+(l>>5)*8+j][strip*32+(l&31)]),
//     still one coalesced f32x4 read + 4 u16 scatters per thread.

#define HID 256
#define TM  32

typedef _Float16 half8  __attribute__((ext_vector_type(8)));
typedef _Float16 half4  __attribute__((ext_vector_type(4)));
typedef float    f32x4  __attribute__((ext_vector_type(4)));
typedef float    f32x16 __attribute__((ext_vector_type(16)));

#define MFMA32 __builtin_amdgcn_mfma_f32_32x32x16_f16

__device__ __forceinline__ float fast_tanh(float z) {
    // tanh(z) = 1 - 2/(exp(2z)+1); saturates correctly at +-inf
    const float e = __expf(2.0f * z);
#if __has_builtin(__builtin_amdgcn_rcpf)
    const float r = __builtin_amdgcn_rcpf(e + 1.0f);
#else
    const float r = 1.0f / (e + 1.0f);
#endif
    return fmaf(-2.0f, r, 1.0f);
}

// Pack W2/W3 (fp32 [256][256], row=k, col=n) into 32x32x16 MFMA A-fragment
// order for W^T, fp16:
//   frag value (kc, strip, lane, j) = W[kc*16 + (lane>>5)*8 + j][strip*32 + (lane&31)]
//   elem index = ((kc*8 + strip)*64 + lane)*8 + j     (kc 0..15, strip 0..7)
// ws layout (f16 elems): W2 @ 0, W3 @ 65536. (256KB total)
// Thread owns one f32x4 of a W row (coalesced read), scatters 4 u16 stores:
//   row -> kc=row>>4, sub=(row>>3)&1, j=row&7;  col -> strip=col>>5, c=col&31;
//   lane = sub*32 + c.
__global__ __launch_bounds__(256) void prep_w(const float* __restrict__ W2,
                                              const float* __restrict__ W3,
                                              _Float16* __restrict__ wsf) {
    const int t = blockIdx.x * 256 + threadIdx.x;     // 0..32767
    const float* __restrict__ W = (t >> 14) ? W3 : W2;
    _Float16* __restrict__ dst = wsf + (size_t)(t >> 14) * 65536;
    const int r    = t & 16383;        // 16384 threads per layer = 256*256/4
    const int row  = r >> 6;           // 0..255  (k index)
    const int col0 = (r & 63) << 2;    // 0,4,...,252
    const f32x4 v = *(const f32x4*)&W[(size_t)row * HID + col0];
    const int kc  = row >> 4;
    const int sub = (row >> 3) & 1;
    const int j   = row & 7;
    #pragma unroll
    for (int c = 0; c < 4; ++c) {
        const int col   = col0 + c;
        const int strip = col >> 5;
        const int lane  = (sub << 5) + (col & 31);
        dst[((size_t)((kc * 8 + strip) * 64 + lane) << 3) + j] = (_Float16)v[c];
    }
}

__global__ __launch_bounds__(256, 2) void pinn_mfma(
    const float* __restrict__ x,
    const float* __restrict__ W1, const float* __restrict__ b1,
    const float* __restrict__ b2, const float* __restrict__ b3,
    const float* __restrict__ W4, const float* __restrict__ b4,
    const _Float16* __restrict__ wsf,
    float* __restrict__ out, int B)
{
    // A-tile: 3 streams x 32 rows x 256 elems fp16, 16B-granule XOR-swizzle:
    // elem(s,row,e) stored at s*8192 + row*256 + (((e>>3) ^ (row&7))<<3) + (e&7)
    __shared__ __align__(16) _Float16 Ahi[3 * 32 * 256];   // 48 KB
    __shared__ float psumW[4][3][TM];                      // 1.5 KB

    const int tid  = threadIdx.x;
    const int s0   = blockIdx.x * TM;
    const int lane = tid & 63;
    const int wave = tid >> 6;          // 0..3

    // ---------- Layer 1: thread owns sample m, 32 consecutive units ----------
    // m mapped so m&7 == tid&7 (conflict-free swizzled writes in 8-lane groups)
    {
        const int m  = (tid & 7) | (((tid >> 3) & 3) << 3);   // 0..31
        const int k0 = (tid >> 5) << 5;                       // 0,32,...,224
        const float2 xv = *(const float2*)&x[(size_t)(s0 + m) * 2];
        const float x0 = xv.x, x1 = xv.y;
        half8 vh[3][4];
        #pragma unroll
        for (int q = 0; q < 4; ++q) {
            #pragma unroll
            for (int h = 0; h < 2; ++h) {
                const int n = k0 + q * 8 + h * 4;
                const f32x4 w0 = *(const f32x4*)&W1[n];
                const f32x4 w1 = *(const f32x4*)&W1[HID + n];
                const f32x4 bb = *(const f32x4*)&b1[n];
                #pragma unroll
                for (int r = 0; r < 4; ++r) {
                    const float z  = fmaf(x0, w0[r], fmaf(x1, w1[r], bb[r]));
                    const float a  = fast_tanh(z);
                    const float sN = 1.0f - a * a;
                    const float ad  = sN * w0[r];
                    const float add = -2.0f * a * ad * w0[r];
                    vh[0][q][h * 4 + r] = (_Float16)a;
                    vh[1][q][h * 4 + r] = (_Float16)ad;
                    vh[2][q][h * 4 + r] = (_Float16)add;
                }
            }
        }
        const int rkm = m & 7;
        const int g0  = k0 >> 3;          // granule base 4*(tid>>5)
        #pragma unroll
        for (int s = 0; s < 3; ++s)
            #pragma unroll
            for (int q = 0; q < 4; ++q)
                *(half8*)&Ahi[s * 8192 + m * 256 + (((g0 + q) ^ rkm) << 3)] = vh[s][q];
    }
    __syncthreads();

    // ---- 32x32x16 MFMA mapping ----
    const int ml5 = lane & 31;           // B/D col = sample (0..31)
    const int hi5 = lane >> 5;           // 0..1 : k-sub (B) / row-sub (D)
    const int rk  = ml5 & 7;             // swizzle key (= row&7)
    const _Float16* __restrict__ Arow = &Ahi[ml5 * 256];

    #pragma unroll 1
    for (int layer = 0; layer < 2; ++layer) {
        // per-wave weight base: strips {wave*2, wave*2+1}; + kc*4096 + st*512
        const _Float16* __restrict__ Wl =
            wsf + ((size_t)layer << 16) + (wave << 10) + (lane << 3);

        f32x16 acc[3][2];                // [stream][strip]
        #pragma unroll
        for (int s = 0; s < 3; ++s)
            #pragma unroll
            for (int st = 0; st < 2; ++st)
                acc[s][st] = (f32x16){0.f,0.f,0.f,0.f,0.f,0.f,0.f,0.f,
                                      0.f,0.f,0.f,0.f,0.f,0.f,0.f,0.f};

        #pragma unroll 1
        for (int kc = 0; kc < 16; ++kc) {
            // B fragments (activations): lane reads sample ml5, k = kc*16+hi5*8..+7
            // granule = (kc*2 + hi5) ^ rk ; one vaddr + stream imm offsets
            const _Float16* __restrict__ Ap =
                Arow + ((((kc << 1) | hi5) ^ rk) << 3);
            const half8 af0 = *(const half8*)&Ap[0];
            const half8 af1 = *(const half8*)&Ap[8192];
            const half8 af2 = *(const half8*)&Ap[16384];
            // A fragments (weights): one vaddr + strip imm offsets
            const _Float16* __restrict__ Wk = Wl + (kc << 12);
            const half8 wf0 = *(const half8*)&Wk[0];
            const half8 wf1 = *(const half8*)&Wk[512];

            __builtin_amdgcn_s_setprio(1);
            acc[0][0] = MFMA32(wf0, af0, acc[0][0], 0, 0, 0);
            acc[1][0] = MFMA32(wf0, af1, acc[1][0], 0, 0, 0);
            acc[2][0] = MFMA32(wf0, af2, acc[2][0], 0, 0, 0);
            acc[0][1] = MFMA32(wf1, af0, acc[0][1], 0, 0, 0);
            acc[1][1] = MFMA32(wf1, af1, acc[1][1], 0, 0, 0);
            acc[2][1] = MFMA32(wf1, af2, acc[2][1], 0, 0, 0);
            __builtin_amdgcn_s_setprio(0);
        }

        __syncthreads();   // all waves done reading A before overwrite / reuse

        if (layer == 0) {
            // ----- layer-2 epilogue: tanh chain, quantize fp16, swizzled write -----
            // D map: col(sample)=ml5, row(unit within strip)= (reg&3)+8*(reg>>2)+4*hi5
            #pragma unroll
            for (int st = 0; st < 2; ++st) {
                const int strip = (wave << 1) + st;
                #pragma unroll
                for (int q = 0; q < 4; ++q) {
                    const int ub = (strip << 5) + (q << 3) + (hi5 << 2); // 4 units
                    const f32x4 bb = *(const f32x4*)&b2[ub];
                    half4 hv[3];
                    #pragma unroll
                    for (int r = 0; r < 4; ++r) {
                        const float z   = acc[0][st][q * 4 + r] + bb[r];
                        const float a   = fast_tanh(z);
                        const float sN  = 1.0f - a * a;
                        const float zd  = acc[1][st][q * 4 + r];
                        const float zdd = acc[2][st][q * 4 + r];
                        const float ad  = sN * zd;
                        const float add = fmaf(sN, zdd, -2.0f * a * ad * zd);
                        hv[0][r] = (_Float16)a;
                        hv[1][r] = (_Float16)ad;
                        hv[2][r] = (_Float16)add;
                    }
                    const int gsw  = ((((strip << 2) + q) ^ rk) << 3) + (hi5 << 2);
                    const int base = ml5 * 256 + gsw;
                    *(half4*)&Ahi[base]         = hv[0];
                    *(half4*)&Ahi[8192  + base] = hv[1];
                    *(half4*)&Ahi[16384 + base] = hv[2];
                }
            }
            __syncthreads();
        } else {
            // ----- layer-3 epilogue fused with W4 dot: all in registers (fp32) -----
            float pd[3] = {0.f, 0.f, 0.f};
            #pragma unroll
            for (int st = 0; st < 2; ++st) {
                const int strip = (wave << 1) + st;
                #pragma unroll
                for (int q = 0; q < 4; ++q) {
                    const int ub = (strip << 5) + (q << 3) + (hi5 << 2);
                    const f32x4 bb = *(const f32x4*)&b3[ub];
                    const f32x4 w4 = *(const f32x4*)&W4[ub];
                    #pragma unroll
                    for (int r = 0; r < 4; ++r) {
                        const float z   = acc[0][st][q * 4 + r] + bb[r];
                        const float a   = fast_tanh(z);
                        const float sN  = 1.0f - a * a;
                        const float zd  = acc[1][st][q * 4 + r];
                        const float zdd = acc[2][st][q * 4 + r];
                        const float ad  = sN * zd;
                        const float add = fmaf(sN, zdd, -2.0f * a * ad * zd);
                        pd[0] = fmaf(a,   w4[r], pd[0]);
                        pd[1] = fmaf(ad,  w4[r], pd[1]);
                        pd[2] = fmaf(add, w4[r], pd[2]);
                    }
                }
            }
            // lanes l and l+32 hold complementary unit-halves of the same sample
            #pragma unroll
            for (int s = 0; s < 3; ++s)
                pd[s] += __shfl_xor(pd[s], 32, 64);
            if (lane < 32) {
                #pragma unroll
                for (int s = 0; s < 3; ++s)
                    psumW[wave][s][lane] = pd[s];
            }
        }
    }
    __syncthreads();

    if (tid < 96) {
        const int s = tid >> 5;          // 0:u 1:du 2:d2u
        const int m = tid & 31;
        const float v = psumW[0][s][m] + psumW[1][s][m]
                      + psumW[2][s][m] + psumW[3][s][m]
                      + ((s == 0) ? b4[0] : 0.0f);
        out[(size_t)s * B + s0 + m] = v;
    }
}

extern "C" void kernel_launch(void* const* d_in, const int* in_sizes, int n_in,
                              void* d_out, int out_size, void* d_ws, size_t ws_size,
                              hipStream_t stream) {
    const float* x  = (const float*)d_in[0];
    const float* W1 = (const float*)d_in[1];
    const float* b1 = (const float*)d_in[2];
    const float* W2 = (const float*)d_in[3];
    const float* b2 = (const float*)d_in[4];
    const float* W3 = (const float*)d_in[5];
    const float* b3 = (const float*)d_in[6];
    const float* W4 = (const float*)d_in[7];
    const float* b4 = (const float*)d_in[8];
    float* out = (float*)d_out;

    const int B = in_sizes[0] / 2;      // x is (B, 2)

    prep_w<<<128, 256, 0, stream>>>(W2, W3, (_Float16*)d_ws);
    pinn_mfma<<<B / TM, 256, 0, stream>>>(x, W1, b1, b2, b3, W4, b4,
                                          (const _Float16*)d_ws, out, B);
}